// Round 11
// baseline (125.234 us; speedup 1.0000x reference)
//
#include <hip/hip_runtime.h>

typedef unsigned short u16;
typedef unsigned int u32;
typedef __bf16 bf16x8 __attribute__((ext_vector_type(8)));
typedef __bf16 bf16x4 __attribute__((ext_vector_type(4)));
typedef short s16x4 __attribute__((ext_vector_type(4)));
typedef float f32x4 __attribute__((ext_vector_type(4)));
typedef u16 u16x4 __attribute__((ext_vector_type(4)));
typedef u16 u16x8 __attribute__((ext_vector_type(8)));

#define LSEQ 2048
#define EMB  1024
#define NH   16
#define HDIM 64

// Q pre-scale: 1/sqrt(64) * log2(e)  (softmax computed in base 2)
#define QSCALE 0.1803368808f

#if __has_builtin(__builtin_amdgcn_exp2f)
#define EXP2(x) __builtin_amdgcn_exp2f(x)
#else
#define EXP2(x) __expf((x) * 0.6931471805599453f)
#endif

// native RTNE f32->bf16 (compiler emits v_cvt_pk_bf16_f32; do NOT hand-roll)
__device__ __forceinline__ u16 cvt_bf(float f) {
  __bf16 h = (__bf16)f;
  return __builtin_bit_cast(u16, h);
}
__device__ __forceinline__ float bf2f(u16 v) {
  return __uint_as_float(((unsigned)v) << 16);
}
__device__ __forceinline__ void async16(void* lds, const void* g) {
  __builtin_amdgcn_global_load_lds((const __attribute__((address_space(1))) void*)g,
                                   (__attribute__((address_space(3))) void*)lds, 16, 0, 0);
}
__device__ __forceinline__ f32x4 mfma16(bf16x8 a, bf16x8 b, f32x4 c) {
  return __builtin_amdgcn_mfma_f32_16x16x32_bf16(a, b, c, 0, 0, 0);
}
// K=16 variant: A/B = 4 bf16 (2 VGPR); A: row=l&15, k=(l>>4)*4+j; B: col=l&15, same k.
__device__ __forceinline__ f32x4 mfma16k16(bf16x4 a, bf16x4 b, f32x4 c) {
#if __has_builtin(__builtin_amdgcn_mfma_f32_16x16x16bf16_1k)
  return __builtin_amdgcn_mfma_f32_16x16x16bf16_1k(
      __builtin_bit_cast(s16x4, a), __builtin_bit_cast(s16x4, b), c, 0, 0, 0);
#else
  asm("v_mfma_f32_16x16x16_bf16 %0, %1, %2, %0" : "+v"(c) : "v"(a), "v"(b));
  return c;
#endif
}

// ---------------- conversion kernels ----------------

// grid-stride: 2048 blocks, 2 float4 per thread
__global__ void f32_to_bf16_vec(const float* __restrict__ in, u16* __restrict__ out, int n4) {
  for (int i = blockIdx.x * 256 + threadIdx.x; i < n4; i += 2048 * 256) {
    float4 v = ((const float4*)in)[i];
    u16x4 o = { cvt_bf(v.x), cvt_bf(v.y), cvt_bf(v.z), cvt_bf(v.w) };
    ((u16x4*)out)[i] = o;
  }
}

// Fused transpose+convert of both weights.
// W_qkv: fp32 [1024][3072] -> bf16 [3072][1024] (bx in 0..95)
// W_o  : fp32 [1024][1024] -> bf16 [1024][1024] (bx in 96..127)
__global__ void transpose_both(const float* __restrict__ Wqkv, u16* __restrict__ WqkvT,
                               const float* __restrict__ Wo, u16* __restrict__ WoT) {
  __shared__ float tile[32][33];
  const int Kd = 1024;
  int bx = blockIdx.x;
  const float* in;
  u16* out;
  int Nd, n0;
  if (bx < 96) { in = Wqkv; out = WqkvT; Nd = 3072; n0 = bx * 32; }
  else         { in = Wo;   out = WoT;   Nd = 1024; n0 = (bx - 96) * 32; }
  int k0 = blockIdx.y * 32;
  int tx = threadIdx.x, ty = threadIdx.y;  // block (32,8)
#pragma unroll
  for (int i = 0; i < 4; ++i)
    tile[ty + i * 8][tx] = in[(size_t)(k0 + ty + i * 8) * Nd + n0 + tx];
  __syncthreads();
#pragma unroll
  for (int i = 0; i < 4; ++i)
    out[(size_t)(n0 + ty + i * 8) * Kd + k0 + tx] = cvt_bf(tile[tx][ty + i * 8]);
}

// ---------------- GEMM (A [M,K] bf16 row-major, Bt [N,K] bf16 row-major) ----------------
// 3-buffer, 2-deep prefetch pipeline with counted vmcnt; BM = 128 or 64 rows.
// MODE 0 (BM=128): QKV epilogue via LDS panes -> coalesced 16B stores.
// MODE 1: fp32 out + bias (direct stores).
template<int NCOLS, int MODE, int BM>
__launch_bounds__(256)
__global__ void gemm_bt(const u16* __restrict__ A, const u16* __restrict__ Bt,
                        const float* __restrict__ bias, float* __restrict__ Out,
                        u16* __restrict__ Qo, u16* __restrict__ Ko, u16* __restrict__ Vo) {
  constexpr int MF = BM / 32;            // per-wave M fragments
  constexpr int ABUF = BM * 32;          // elems per A buffer
  // merged SMEM: staging (As 3 bufs + Bs 3 bufs) reused as epilogue panes
  __shared__ __attribute__((aligned(16))) u16 SMEM[3 * ABUF + 3 * 128 * 32];
  u16* As = SMEM;
  u16* Bs = SMEM + 3 * ABUF;
  const int tid = threadIdx.x;
  const int w = tid >> 6, l = tid & 63;
  const int g = l >> 4, cc = l & 15;
  // XCD-bijective swizzle (nwg % 8 == 0)
  constexpr int GX = NCOLS / 128;
  constexpr int NWG = (4096 / BM) * GX;
  constexpr int CPX = NWG / 8;
  const int orig = blockIdx.y * GX + blockIdx.x;
  const int wgid = (orig & 7) * CPX + (orig >> 3);
  const int m0 = (wgid / GX) * BM, n0 = (wgid % GX) * 128;
  const int wm = w >> 1, wn = w & 1;
  const int K = 1024;
  const int srow = tid >> 2;            // staging row (+64 per chunk)
  const int scol = (tid & 3) * 8;       // staging col (elements)
  const u16* Ag = A + (size_t)(m0 + srow) * K + scol;
  const u16* Bg = Bt + (size_t)(n0 + srow) * K + scol;
  f32x4 acc[MF][4] = {};

  auto stage = [&](int buf, int k0) {
    async16(&As[buf * ABUF + w * 512], Ag + k0);
    if constexpr (BM == 128)
      async16(&As[buf * ABUF + 2048 + w * 512], Ag + (size_t)64 * K + k0);
    async16(&Bs[buf * 4096 + w * 512], Bg + k0);
    async16(&Bs[buf * 4096 + 2048 + w * 512], Bg + (size_t)64 * K + k0);
  };

  stage(0, 0);
  stage(1, 32);
  int buf = 0;
  for (int k0 = 0; k0 < K; k0 += 32) {
    // wait for this step's stage (leave the newest stage's loads in flight)
    if (k0 + 32 < K) {
      if constexpr (BM == 128) asm volatile("s_waitcnt vmcnt(4)" ::: "memory");
      else                     asm volatile("s_waitcnt vmcnt(3)" ::: "memory");
    } else {
      asm volatile("s_waitcnt vmcnt(0)" ::: "memory");
    }
    __builtin_amdgcn_s_barrier();
    __builtin_amdgcn_sched_barrier(0);
    if (k0 + 64 < K) {
      int nb = buf + 2; if (nb >= 3) nb -= 3;
      stage(nb, k0 + 64);
    }
    bf16x8 af[MF], bfr[4];
#pragma unroll
    for (int mf = 0; mf < MF; ++mf)
      af[mf] = *(const bf16x8*)&As[buf * ABUF + (wm * (BM / 2) + mf * 16 + cc) * 32 + g * 8];
#pragma unroll
    for (int nf = 0; nf < 4; ++nf)
      bfr[nf] = *(const bf16x8*)&Bs[buf * 4096 + (wn * 64 + nf * 16 + cc) * 32 + g * 8];
#pragma unroll
    for (int mf = 0; mf < MF; ++mf)
#pragma unroll
      for (int nf = 0; nf < 4; ++nf)
        acc[mf][nf] = mfma16(af[mf], bfr[nf], acc[mf][nf]);
    if (++buf == 3) buf = 0;
  }

  if constexpr (MODE == 0) {
    // ---- epilogue via LDS panes (coalesced stores) ----
    __syncthreads();                       // staging reads done; SMEM reusable
    char* pane0 = (char*)SMEM;             // 24KB half
    char* pane1 = (char*)(SMEM + 3 * ABUF);
    const int bb = m0 >> 11;
    {
      // this wave's window
      const int nbase = n0 + wn * 64;
      const int hd = nbase / 192, rem = nbase - hd * 192, which = rem >> 6;
      char* P = wn ? pane1 : pane0;
#pragma unroll
      for (int mf = 0; mf < MF; ++mf) {
#pragma unroll
        for (int nf = 0; nf < 4; ++nf) {
          int d = nf * 16 + cc;
          float bv = bias[nbase + d];
#pragma unroll
          for (int r = 0; r < 4; ++r) {
            int ml = wm * 64 + mf * 16 + g * 4 + r;
            float val = acc[mf][nf][r] + bv;
            if (which == 0) val *= QSCALE;
            u16 h = cvt_bf(val);
            if (which == 2) *(u16*)(P + d * 272 + ml * 2) = h;
            else            *(u16*)(P + ml * 144 + d * 2) = h;
          }
        }
      }
    }
    __syncthreads();
    // cooperative coalesced stores for both windows
#pragma unroll
    for (int wi = 0; wi < 2; ++wi) {
      const int nb = n0 + wi * 64;
      const int hd = nb / 192, rem = nb - hd * 192, wh = rem >> 6;
      const int bh = bb * NH + hd;
      const int ls0 = m0 & (LSEQ - 1);
      char* P = wi ? pane1 : pane0;
      if (wh == 2) {
        // V: 64 rows(d) x 256B, dst row stride = LSEQ*2B
        u16* dstb = Vo + (size_t)bh * HDIM * LSEQ + ls0;
#pragma unroll
        for (int it = 0; it < 4; ++it) {
          int idx = it * 256 + tid;
          int row = idx >> 4;
          int colB = (idx & 15) * 16;
          int4 v = *(const int4*)(P + row * 272 + colB);
          *(int4*)((char*)(dstb + (size_t)row * LSEQ) + colB) = v;
        }
      } else {
        // Q/K: 128 rows(ml) x 128B -> contiguous 16KB at dst
        u16* dst = (wh == 0 ? Qo : Ko) + ((size_t)bh * LSEQ + ls0) * HDIM;
#pragma unroll
        for (int it = 0; it < 4; ++it) {
          int idx = it * 256 + tid;
          int row = idx >> 3;
          int colB = (idx & 7) * 16;
          int4 v = *(const int4*)(P + row * 144 + colB);
          *(int4*)((char*)dst + row * 128 + colB) = v;
        }
      }
    }
  } else {
    // MODE 1: direct fp32 stores + bias
#pragma unroll
    for (int mf = 0; mf < MF; ++mf) {
#pragma unroll
      for (int nf = 0; nf < 4; ++nf) {
        int n = n0 + wn * 64 + nf * 16 + cc;
        float bv = bias[n];
#pragma unroll
        for (int r = 0; r < 4; ++r) {
          int m = m0 + wm * (BM / 2) + mf * 16 + g * 4 + r;
          Out[(size_t)m * NCOLS + n] = acc[mf][nf][r] + bv;
        }
      }
    }
  }
}

// ---------------- flash attention ----------------
// Q,K: bf16 [B*H, L, D] (Q pre-scaled by QSCALE -> softmax in base 2);
// Vt: bf16 [B*H, D, L]; Y: bf16 [B, L, H*D]. Causal; rows >= mask_len fixed by
// meanv_fill. LDS-staged K/V, double-buffered with COUNTED vmcnt(4) + raw
// s_barrier. 1024 blocks, 4/CU; balanced qblk interleave {31-j, j, 23-j, 8+j}.
// R11: SWAPPED QK^T + K=16 PV -- P never leaves registers.
//   S^T = mfma(kf, qf): lane(g,cc) holds S[q=cc][kv=nf*16+g*4+r] (same frag
//   loads as before, operands swapped). Static-max (R10) means no row-reduce.
//   The lane's 4 P-values per nf ARE a 16x16x16 A-fragment (k=(l>>4)*4+j), so
//   PV = 16 K=16 MFMAs reading V B-frags as ds_read_b64; lsum via ones-MFMA
//   (B-side, same register). Deletes the entire P LDS round-trip (16 write +
//   2 read + lgkmcnt serialize) and the Ps buffer.
__launch_bounds__(256)
__global__ void attn_fwd(const u16* __restrict__ Q, const u16* __restrict__ Kb,
                         const u16* __restrict__ Vt, u16* __restrict__ Y) {
  __shared__ __attribute__((aligned(16))) u16 Ks[2][64 * 64];
  __shared__ __attribute__((aligned(16))) u16 Vs[2][64 * 64];
  const int tid = threadIdx.x;
  const int w = tid >> 6, l = tid & 63;
  const int g = l >> 4, cc = l & 15;

  const int i = blockIdx.x;
  const int bh = i & 31;                 // XCD = i%8 -> 4 bh per XCD L2
  const int k = i >> 5, grp = k >> 3, j = k & 7;
  int qblk;
  if (grp == 0) qblk = 31 - j;
  else if (grp == 1) qblk = j;
  else if (grp == 2) qblk = 23 - j;
  else qblk = 8 + j;
  const int q0 = qblk * 64;
  const int nt = qblk + 1;

  const int sr = w * 8 + (l >> 3);   // staging row (+ chunk*32)
  const int pb = (l & 7) * 16;       // physical byte within 128B row
  const int xc = (cc & 7) << 4;
  const int b = bh >> 4, h = bh & (NH - 1);

  auto stageKV = [&](int buf, int t) {
    const int kv0 = t * 64;
#pragma unroll
    for (int ch = 0; ch < 2; ++ch) {
      int R = sr + ch * 32;
      int dcol = (pb ^ ((R & 7) << 4)) >> 1;  // pre-swizzled global source
      async16((char*)Ks[buf] + ch * 4096 + w * 1024,
              Kb + ((size_t)bh * LSEQ + kv0 + R) * HDIM + dcol);
      async16((char*)Vs[buf] + ch * 4096 + w * 1024,
              Vt + ((size_t)bh * HDIM + R) * LSEQ + kv0 + dcol);
    }
  };

  const u16* Qg = Q + ((size_t)bh * LSEQ + q0 + w * 16) * HDIM;
  bf16x8 qf0 = *(const bf16x8*)&Qg[cc * HDIM + g * 8];
  bf16x8 qf1 = *(const bf16x8*)&Qg[cc * HDIM + 32 + g * 8];

  bf16x4 ones4;
#pragma unroll
  for (int z = 0; z < 4; ++z) ones4[z] = (__bf16)1.0f;

  f32x4 o[4] = {};
  f32x4 ls16 = {};   // lane(g,cc): lsum[q=cc] broadcast in all regs

  stageKV(0, 0);

  for (int t = 0; t < nt; ++t) {
    const int cur = t & 1;
    // issue next-tile prefetch, then wait ONLY for this tile's 4 loads
    if (t + 1 < nt) {
      stageKV(cur ^ 1, t + 1);
      asm volatile("s_waitcnt vmcnt(4)" ::: "memory");
    } else {
      asm volatile("s_waitcnt vmcnt(0)" ::: "memory");
    }
    __builtin_amdgcn_s_barrier();          // tile-t data visible to all waves
    __builtin_amdgcn_sched_barrier(0);
    const char* KsB = (const char*)Ks[cur];
    const char* VsB = (const char*)Vs[cur];

    // S^T = K Q^T (operands swapped): lane holds S[q=cc][kv=nf*16+g*4+r]
    f32x4 sf[4] = {};
    __builtin_amdgcn_s_setprio(1);
#pragma unroll
    for (int nf = 0; nf < 4; ++nf) {
      bf16x8 kf0 = *(const bf16x8*)(KsB + (nf * 16 + cc) * 128 + ((g * 16) ^ xc));
      bf16x8 kf1 = *(const bf16x8*)(KsB + (nf * 16 + cc) * 128 + ((64 + g * 16) ^ xc));
      sf[nf] = mfma16(kf0, qf0, sf[nf]);
      sf[nf] = mfma16(kf1, qf1, sf[nf]);
    }
    __builtin_amdgcn_s_setprio(0);

    if (t == nt - 1) {  // diagonal tile: causal mask (kv_local > q_local)
#pragma unroll
      for (int nf = 0; nf < 4; ++nf) {
#pragma unroll
        for (int r = 0; r < 4; ++r)
          if (nf * 16 + g * 4 + r > w * 16 + cc) sf[nf][r] = -1e30f;
      }
    }

    // P = exp2(S) packed straight into K=16 A-fragments (static max = 0)
    bf16x4 pA[4];
#pragma unroll
    for (int nf = 0; nf < 4; ++nf) {
      bf16x4 pv = { (__bf16)EXP2(sf[nf][0]), (__bf16)EXP2(sf[nf][1]),
                    (__bf16)EXP2(sf[nf][2]), (__bf16)EXP2(sf[nf][3]) };
      pA[nf] = pv;
    }

    // O += P V and lsum += row-sums, all K=16 MFMAs; V B-frags via ds_read_b64
    __builtin_amdgcn_s_setprio(1);
#pragma unroll
    for (int s = 0; s < 4; ++s) {
      ls16 = mfma16k16(ones4, pA[s], ls16);
#pragma unroll
      for (int nf = 0; nf < 4; ++nf) {
        bf16x4 vB = *(const bf16x4*)(VsB + (nf * 16 + cc) * 128 + ((s * 32 + g * 8) ^ xc));
        o[nf] = mfma16k16(pA[s], vB, o[nf]);
      }
    }
    __builtin_amdgcn_s_setprio(0);
    // WAR guard: all waves done reading buffer `cur` before it is re-staged
    // next iteration. Raw barrier -- no vmcnt drain (prefetch stays in flight).
    __builtin_amdgcn_s_barrier();
  }

  // epilogue: Y[b, q, h*64 + d]; lsum[q] lives at lane cc=q -> shfl redistribute
#pragma unroll
  for (int r = 0; r < 4; ++r) {
    float lr = __shfl(ls16[0], g * 4 + r);
    float inv = 1.0f / lr;
    int row = q0 + w * 16 + g * 4 + r;
    size_t base = ((size_t)b * LSEQ + row) * EMB + h * HDIM;
#pragma unroll
    for (int nf = 0; nf < 4; ++nf)
      Y[base + nf * 16 + cc] = cvt_bf(o[nf][r] * inv);
  }
}

// ---------------- mean-V fixup for rows >= mask_len ----------------
__global__ void meanv_fill(const u16* __restrict__ Vt, const int* __restrict__ mask_len,
                           u16* __restrict__ Y) {
  __shared__ float partial[256];
  __shared__ u16 mv[HDIM];
  int bh = blockIdx.x, b = bh >> 4, h = bh & (NH - 1);
  int tid = threadIdx.x;
  int d = tid >> 2, part = tid & 3;
  const u16* src = Vt + ((size_t)bh * HDIM + d) * LSEQ + part * 512;
  float s = 0.f;
  for (int i = 0; i < 512; i += 8) {
    u16x8 v = *(const u16x8*)&src[i];
#pragma unroll
    for (int j = 0; j < 8; ++j) s += bf2f(v[j]);
  }
  partial[tid] = s;
  __syncthreads();
  if (part == 0) {
    float t = partial[tid] + partial[tid + 1] + partial[tid + 2] + partial[tid + 3];
    mv[d] = cvt_bf(t * (1.0f / (float)LSEQ));
  }
  __syncthreads();
  int lo = mask_len[b];
  if (lo < 0) lo = 0;
  if (lo > LSEQ) lo = LSEQ;
  int total = (LSEQ - lo) * HDIM;
  for (int idx = tid; idx < total; idx += 256) {
    int row = lo + (idx >> 6), dd = idx & 63;
    Y[((size_t)b * LSEQ + row) * EMB + h * HDIM + dd] = mv[dd];
  }
}

// ---------------- launch ----------------
extern "C" void kernel_launch(void* const* d_in, const int* in_sizes, int n_in,
                              void* d_out, int out_size, void* d_ws, size_t ws_size,
                              hipStream_t stream) {
  (void)in_sizes; (void)n_in; (void)out_size; (void)ws_size;
  const float* x    = (const float*)d_in[0];
  const float* Wqkv = (const float*)d_in[1];
  const float* bqkv = (const float*)d_in[2];
  const float* Wo   = (const float*)d_in[3];
  const float* bo   = (const float*)d_in[4];
  const int* mask_len = (const int*)d_in[5];
  float* out = (float*)d_out;

  u16* ws = (u16*)d_ws;
  u16* xb    = ws;                              // 4M elems (x bf16) — reused as Y later
  u16* wqkvt = ws + (size_t)4 * 1024 * 1024;    // 3M (W_qkv^T bf16)
  u16* wot   = wqkvt + (size_t)3 * 1024 * 1024; // 1M (W_o^T bf16)
  u16* Qb    = wot + (size_t)1024 * 1024;       // 4M
  u16* Kb    = Qb + (size_t)4 * 1024 * 1024;    // 4M
  u16* Vtb   = Kb + (size_t)4 * 1024 * 1024;    // 4M
  u16* Yb    = xb;                              // alias: x dead after gemm_qkv

  f32_to_bf16_vec<<<2048, 256, 0, stream>>>(x, xb, 1024 * 1024);
  transpose_both<<<dim3(128, 32), dim3(32, 8), 0, stream>>>(Wqkv, wqkvt, Wo, wot);
  gemm_bt<3072, 0, 128><<<dim3(24, 32), 256, 0, stream>>>(xb, wqkvt, bqkv, nullptr, Qb, Kb, Vtb);
  attn_fwd<<<1024, 256, 0, stream>>>(Qb, Kb, Vtb, Yb);
  meanv_fill<<<32, 256, 0, stream>>>(Vtb, mask_len, Yb);
  gemm_bt<1024, 1, 64><<<dim3(8, 64), 256, 0, stream>>>(Yb, wot, bo, out, nullptr, nullptr, nullptr);
}

// Round 12
// 98.167 us; speedup vs baseline: 1.2757x; 1.2757x over previous
//
#include <hip/hip_runtime.h>

typedef unsigned short u16;
typedef unsigned int u32;
typedef __bf16 bf16x8 __attribute__((ext_vector_type(8)));
typedef float f32x4 __attribute__((ext_vector_type(4)));
typedef u16 u16x4 __attribute__((ext_vector_type(4)));
typedef u16 u16x8 __attribute__((ext_vector_type(8)));

#define LSEQ 2048
#define EMB  1024
#define NH   16
#define HDIM 64

// Q pre-scale: 1/sqrt(64) * log2(e)  (softmax computed in base 2)
#define QSCALE 0.1803368808f

#if __has_builtin(__builtin_amdgcn_exp2f)
#define EXP2(x) __builtin_amdgcn_exp2f(x)
#else
#define EXP2(x) __expf((x) * 0.6931471805599453f)
#endif

// native RTNE f32->bf16 (compiler emits v_cvt_pk_bf16_f32; do NOT hand-roll)
__device__ __forceinline__ u16 cvt_bf(float f) {
  __bf16 h = (__bf16)f;
  return __builtin_bit_cast(u16, h);
}
__device__ __forceinline__ float bf2f(u16 v) {
  return __uint_as_float(((unsigned)v) << 16);
}
__device__ __forceinline__ void async16(void* lds, const void* g) {
  __builtin_amdgcn_global_load_lds((const __attribute__((address_space(1))) void*)g,
                                   (__attribute__((address_space(3))) void*)lds, 16, 0, 0);
}
__device__ __forceinline__ f32x4 mfma16(bf16x8 a, bf16x8 b, f32x4 c) {
  return __builtin_amdgcn_mfma_f32_16x16x32_bf16(a, b, c, 0, 0, 0);
}

// ---------------- fused prep: x conversion + both weight transposes ----------------
// blocks 0..2047:   x fp32 [1M float4] -> bf16 (grid-stride)
// blocks 2048..6143: transpose W_qkv (idx<96*32 over bx 0..127 split) / W_o
__global__ void prep(const float* __restrict__ x, u16* __restrict__ xb,
                     const float* __restrict__ Wqkv, u16* __restrict__ WqkvT,
                     const float* __restrict__ Wo, u16* __restrict__ WoT) {
  __shared__ float tile[32][33];
  const int bid = blockIdx.x;
  const int tid = threadIdx.x;
  if (bid < 2048) {
    const int n4 = 1024 * 1024;
    for (int i = bid * 256 + tid; i < n4; i += 2048 * 256) {
      float4 v = ((const float4*)x)[i];
      u16x4 o = { cvt_bf(v.x), cvt_bf(v.y), cvt_bf(v.z), cvt_bf(v.w) };
      ((u16x4*)xb)[i] = o;
    }
    return;
  }
  const int idx = bid - 2048;          // 0..4095
  const int bx = idx & 127, by = idx >> 7;
  const int Kd = 1024;
  const float* in;
  u16* out;
  int Nd, n0;
  if (bx < 96) { in = Wqkv; out = WqkvT; Nd = 3072; n0 = bx * 32; }
  else         { in = Wo;   out = WoT;   Nd = 1024; n0 = (bx - 96) * 32; }
  const int k0 = by * 32;
  const int tx = tid & 31, ty = tid >> 5;   // (32,8)
#pragma unroll
  for (int i = 0; i < 4; ++i)
    tile[ty + i * 8][tx] = in[(size_t)(k0 + ty + i * 8) * Nd + n0 + tx];
  __syncthreads();
#pragma unroll
  for (int i = 0; i < 4; ++i)
    out[(size_t)(n0 + ty + i * 8) * Kd + k0 + tx] = cvt_bf(tile[tx][ty + i * 8]);
}

// ---------------- GEMM (A [M,K] bf16 row-major, Bt [N,K] bf16 row-major) ----------------
// 3-buffer, 2-deep prefetch pipeline with counted vmcnt; BM = 128 or 64 rows.
// MODE 0 (BM=128): QKV epilogue via LDS panes -> coalesced 16B stores.
// MODE 1: fp32 out + bias (direct stores).
template<int NCOLS, int MODE, int BM>
__launch_bounds__(256)
__global__ void gemm_bt(const u16* __restrict__ A, const u16* __restrict__ Bt,
                        const float* __restrict__ bias, float* __restrict__ Out,
                        u16* __restrict__ Qo, u16* __restrict__ Ko, u16* __restrict__ Vo) {
  constexpr int MF = BM / 32;            // per-wave M fragments
  constexpr int ABUF = BM * 32;          // elems per A buffer
  __shared__ __attribute__((aligned(16))) u16 SMEM[3 * ABUF + 3 * 128 * 32];
  u16* As = SMEM;
  u16* Bs = SMEM + 3 * ABUF;
  const int tid = threadIdx.x;
  const int w = tid >> 6, l = tid & 63;
  const int g = l >> 4, cc = l & 15;
  constexpr int GX = NCOLS / 128;
  constexpr int NWG = (4096 / BM) * GX;
  constexpr int CPX = NWG / 8;
  const int orig = blockIdx.y * GX + blockIdx.x;
  const int wgid = (orig & 7) * CPX + (orig >> 3);
  const int m0 = (wgid / GX) * BM, n0 = (wgid % GX) * 128;
  const int wm = w >> 1, wn = w & 1;
  const int K = 1024;
  const int srow = tid >> 2;
  const int scol = (tid & 3) * 8;
  const u16* Ag = A + (size_t)(m0 + srow) * K + scol;
  const u16* Bg = Bt + (size_t)(n0 + srow) * K + scol;
  f32x4 acc[MF][4] = {};

  auto stage = [&](int buf, int k0) {
    async16(&As[buf * ABUF + w * 512], Ag + k0);
    if constexpr (BM == 128)
      async16(&As[buf * ABUF + 2048 + w * 512], Ag + (size_t)64 * K + k0);
    async16(&Bs[buf * 4096 + w * 512], Bg + k0);
    async16(&Bs[buf * 4096 + 2048 + w * 512], Bg + (size_t)64 * K + k0);
  };

  stage(0, 0);
  stage(1, 32);
  int buf = 0;
  for (int k0 = 0; k0 < K; k0 += 32) {
    if (k0 + 32 < K) {
      if constexpr (BM == 128) asm volatile("s_waitcnt vmcnt(4)" ::: "memory");
      else                     asm volatile("s_waitcnt vmcnt(3)" ::: "memory");
    } else {
      asm volatile("s_waitcnt vmcnt(0)" ::: "memory");
    }
    __builtin_amdgcn_s_barrier();
    __builtin_amdgcn_sched_barrier(0);
    if (k0 + 64 < K) {
      int nb = buf + 2; if (nb >= 3) nb -= 3;
      stage(nb, k0 + 64);
    }
    bf16x8 af[MF], bfr[4];
#pragma unroll
    for (int mf = 0; mf < MF; ++mf)
      af[mf] = *(const bf16x8*)&As[buf * ABUF + (wm * (BM / 2) + mf * 16 + cc) * 32 + g * 8];
#pragma unroll
    for (int nf = 0; nf < 4; ++nf)
      bfr[nf] = *(const bf16x8*)&Bs[buf * 4096 + (wn * 64 + nf * 16 + cc) * 32 + g * 8];
#pragma unroll
    for (int mf = 0; mf < MF; ++mf)
#pragma unroll
      for (int nf = 0; nf < 4; ++nf)
        acc[mf][nf] = mfma16(af[mf], bfr[nf], acc[mf][nf]);
    if (++buf == 3) buf = 0;
  }

  if constexpr (MODE == 0) {
    // ---- epilogue via LDS panes (coalesced stores) ----
    __syncthreads();
    char* pane0 = (char*)SMEM;
    char* pane1 = (char*)(SMEM + 3 * ABUF);
    const int bb = m0 >> 11;
    {
      const int nbase = n0 + wn * 64;
      const int hd = nbase / 192, rem = nbase - hd * 192, which = rem >> 6;
      char* P = wn ? pane1 : pane0;
#pragma unroll
      for (int mf = 0; mf < MF; ++mf) {
#pragma unroll
        for (int nf = 0; nf < 4; ++nf) {
          int d = nf * 16 + cc;
          float bv = bias[nbase + d];
#pragma unroll
          for (int r = 0; r < 4; ++r) {
            int ml = wm * 64 + mf * 16 + g * 4 + r;
            float val = acc[mf][nf][r] + bv;
            if (which == 0) val *= QSCALE;
            u16 h = cvt_bf(val);
            if (which == 2) *(u16*)(P + d * 272 + ml * 2) = h;
            else            *(u16*)(P + ml * 144 + d * 2) = h;
          }
        }
      }
    }
    __syncthreads();
#pragma unroll
    for (int wi = 0; wi < 2; ++wi) {
      const int nb = n0 + wi * 64;
      const int hd = nb / 192, rem = nb - hd * 192, wh = rem >> 6;
      const int bh = bb * NH + hd;
      const int ls0 = m0 & (LSEQ - 1);
      char* P = wi ? pane1 : pane0;
      if (wh == 2) {
        u16* dstb = Vo + (size_t)bh * HDIM * LSEQ + ls0;
#pragma unroll
        for (int it = 0; it < 4; ++it) {
          int idx = it * 256 + tid;
          int row = idx >> 4;
          int colB = (idx & 15) * 16;
          int4 v = *(const int4*)(P + row * 272 + colB);
          *(int4*)((char*)(dstb + (size_t)row * LSEQ) + colB) = v;
        }
      } else {
        u16* dst = (wh == 0 ? Qo : Ko) + ((size_t)bh * LSEQ + ls0) * HDIM;
#pragma unroll
        for (int it = 0; it < 4; ++it) {
          int idx = it * 256 + tid;
          int row = idx >> 3;
          int colB = (idx & 7) * 16;
          int4 v = *(const int4*)(P + row * 144 + colB);
          *(int4*)((char*)dst + row * 128 + colB) = v;
        }
      }
    }
  } else {
#pragma unroll
    for (int mf = 0; mf < MF; ++mf) {
#pragma unroll
      for (int nf = 0; nf < 4; ++nf) {
        int n = n0 + wn * 64 + nf * 16 + cc;
        float bv = bias[n];
#pragma unroll
        for (int r = 0; r < 4; ++r) {
          int m = m0 + wm * (BM / 2) + mf * 16 + g * 4 + r;
          Out[(size_t)m * NCOLS + n] = acc[mf][nf][r] + bv;
        }
      }
    }
  }
}

// ---------------- flash attention + fused meanv ----------------
// R12: R10 body (static-max, MFMA-ones lsum, counted vmcnt, P LDS round-trip,
// 0 conflicts) + mask_len awareness:
//  - blocks with q0 >= mask_len[b] return immediately (their rows are mean-V,
//    written by the meanv blocks) -- skips staging + full KV loop.
//  - straddling blocks guard stores per-row (row < lo).
//  - blocks 1024..1055 run the meanv fill (scratch aliased into Ks). Row
//    ownership is disjoint -> race-free within one launch.
__launch_bounds__(256)
__global__ void attn_fwd(const u16* __restrict__ Q, const u16* __restrict__ Kb,
                         const u16* __restrict__ Vt, const int* __restrict__ mask_len,
                         u16* __restrict__ Y) {
  __shared__ __attribute__((aligned(16))) u16 Ks[2][64 * 64];
  __shared__ __attribute__((aligned(16))) u16 Vs[2][64 * 64];
  __shared__ __attribute__((aligned(16))) u16 Ps[4 * 16 * 64];
  const int tid = threadIdx.x;
  const int i = blockIdx.x;

  if (i >= 1024) {
    // ---- meanv fill: Y[b, row>=lo, h*64+d] = mean_kv V ----
    float* partial = (float*)Ks;
    u16* mv = (u16*)((char*)Ks + 1024);
    int bh = i - 1024, b = bh >> 4, h = bh & (NH - 1);
    int d = tid >> 2, part = tid & 3;
    const u16* src = Vt + ((size_t)bh * HDIM + d) * LSEQ + part * 512;
    float s = 0.f;
    for (int ii = 0; ii < 512; ii += 8) {
      u16x8 v = *(const u16x8*)&src[ii];
#pragma unroll
      for (int jj = 0; jj < 8; ++jj) s += bf2f(v[jj]);
    }
    partial[tid] = s;
    __syncthreads();
    if (part == 0) {
      float t = partial[tid] + partial[tid + 1] + partial[tid + 2] + partial[tid + 3];
      mv[d] = cvt_bf(t * (1.0f / (float)LSEQ));
    }
    __syncthreads();
    int lo = mask_len[b];
    if (lo < 0) lo = 0;
    if (lo > LSEQ) lo = LSEQ;
    int total = (LSEQ - lo) * HDIM;
    for (int idx = tid; idx < total; idx += 256) {
      int row = lo + (idx >> 6), dd = idx & 63;
      Y[((size_t)b * LSEQ + row) * EMB + h * HDIM + dd] = mv[dd];
    }
    return;
  }

  const int w = tid >> 6, l = tid & 63;
  const int g = l >> 4, cc = l & 15;
  const int bh = i & 31;                 // XCD = i%8 -> 4 bh per XCD L2
  const int k = i >> 5, grp = k >> 3, j = k & 7;
  int qblk;
  if (grp == 0) qblk = 31 - j;
  else if (grp == 1) qblk = j;
  else if (grp == 2) qblk = 23 - j;
  else qblk = 8 + j;
  const int q0 = qblk * 64;
  const int nt = qblk + 1;
  const int b = bh >> 4, h = bh & (NH - 1);

  // rows >= lo are mean-V rows (written by meanv blocks): skip whole block
  const int lo = mask_len[b];
  if (q0 >= lo) return;

  const int sr = w * 8 + (l >> 3);   // staging row (+ chunk*32)
  const int pb = (l & 7) * 16;       // physical byte within 128B row
  char* Pw = (char*)&Ps[w * 16 * 64];
  const int xc = (cc & 7) << 4;

  auto stageKV = [&](int buf, int t) {
    const int kv0 = t * 64;
#pragma unroll
    for (int ch = 0; ch < 2; ++ch) {
      int R = sr + ch * 32;
      int dcol = (pb ^ ((R & 7) << 4)) >> 1;  // pre-swizzled global source
      async16((char*)Ks[buf] + ch * 4096 + w * 1024,
              Kb + ((size_t)bh * LSEQ + kv0 + R) * HDIM + dcol);
      async16((char*)Vs[buf] + ch * 4096 + w * 1024,
              Vt + ((size_t)bh * HDIM + R) * LSEQ + kv0 + dcol);
    }
  };

  const u16* Qg = Q + ((size_t)bh * LSEQ + q0 + w * 16) * HDIM;
  bf16x8 qf0 = *(const bf16x8*)&Qg[cc * HDIM + g * 8];
  bf16x8 qf1 = *(const bf16x8*)&Qg[cc * HDIM + 32 + g * 8];

  bf16x8 onesf;
#pragma unroll
  for (int z = 0; z < 8; ++z) onesf[z] = (__bf16)1.0f;

  f32x4 o[4] = {};
  f32x4 ls = {};

  stageKV(0, 0);

  for (int t = 0; t < nt; ++t) {
    const int cur = t & 1;
    if (t + 1 < nt) {
      stageKV(cur ^ 1, t + 1);
      asm volatile("s_waitcnt vmcnt(4)" ::: "memory");
    } else {
      asm volatile("s_waitcnt vmcnt(0)" ::: "memory");
    }
    __builtin_amdgcn_s_barrier();
    __builtin_amdgcn_sched_barrier(0);
    const char* KsB = (const char*)Ks[cur];
    const char* VsB = (const char*)Vs[cur];

    // S = Q K^T (base-2 scaled); C: row=q (g*4+r), col=kv (cc) per nf-frag
    f32x4 sf[4] = {};
    __builtin_amdgcn_s_setprio(1);
#pragma unroll
    for (int nf = 0; nf < 4; ++nf) {
      bf16x8 kf0 = *(const bf16x8*)(KsB + (nf * 16 + cc) * 128 + ((g * 16) ^ xc));
      bf16x8 kf1 = *(const bf16x8*)(KsB + (nf * 16 + cc) * 128 + ((64 + g * 16) ^ xc));
      sf[nf] = mfma16(qf0, kf0, sf[nf]);
      sf[nf] = mfma16(qf1, kf1, sf[nf]);
    }
    __builtin_amdgcn_s_setprio(0);

    if (t == nt - 1) {  // diagonal tile: causal mask
#pragma unroll
      for (int nf = 0; nf < 4; ++nf) {
        int kvl = nf * 16 + cc;
#pragma unroll
        for (int r = 0; r < 4; ++r)
          if (kvl > w * 16 + g * 4 + r) sf[nf][r] = -1e30f;
      }
    }

    // P = exp2(S) (static max; logits bounded), write to per-wave LDS
#pragma unroll
    for (int r = 0; r < 4; ++r) {
      int q = g * 4 + r;
      int xr = (q & 7) << 4;
#pragma unroll
      for (int nf = 0; nf < 4; ++nf) {
        float pv = EXP2(sf[nf][r]);
        *(u16*)(Pw + q * 128 + (((nf * 16 + cc) * 2) ^ xr)) = cvt_bf(pv);
      }
    }
    asm volatile("s_waitcnt lgkmcnt(0)" ::: "memory");
    __builtin_amdgcn_sched_barrier(0);

    bf16x8 pf0 = *(const bf16x8*)(Pw + cc * 128 + ((g * 16) ^ xc));
    bf16x8 pf1 = *(const bf16x8*)(Pw + cc * 128 + ((64 + g * 16) ^ xc));
    __builtin_amdgcn_s_setprio(1);
    ls = mfma16(pf1, onesf, mfma16(pf0, onesf, ls));
#pragma unroll
    for (int nf = 0; nf < 4; ++nf) {
      bf16x8 vf0 = *(const bf16x8*)(VsB + (nf * 16 + cc) * 128 + ((g * 16) ^ xc));
      bf16x8 vf1 = *(const bf16x8*)(VsB + (nf * 16 + cc) * 128 + ((64 + g * 16) ^ xc));
      o[nf] = mfma16(pf0, vf0, o[nf]);
      o[nf] = mfma16(pf1, vf1, o[nf]);
    }
    __builtin_amdgcn_s_setprio(0);
    __builtin_amdgcn_s_barrier();   // WAR guard; no vmcnt drain
  }

  // epilogue: Y[b, q, h*64 + d]; only rows < lo (mean rows owned by meanv blocks)
#pragma unroll
  for (int r = 0; r < 4; ++r) {
    int row = q0 + w * 16 + g * 4 + r;
    if (row < lo) {
      float inv = 1.0f / ls[r];
      size_t base = ((size_t)b * LSEQ + row) * EMB + h * HDIM;
#pragma unroll
      for (int nf = 0; nf < 4; ++nf)
        Y[base + nf * 16 + cc] = cvt_bf(o[nf][r] * inv);
    }
  }
}

// ---------------- launch ----------------
extern "C" void kernel_launch(void* const* d_in, const int* in_sizes, int n_in,
                              void* d_out, int out_size, void* d_ws, size_t ws_size,
                              hipStream_t stream) {
  (void)in_sizes; (void)n_in; (void)out_size; (void)ws_size;
  const float* x    = (const float*)d_in[0];
  const float* Wqkv = (const float*)d_in[1];
  const float* bqkv = (const float*)d_in[2];
  const float* Wo   = (const float*)d_in[3];
  const float* bo   = (const float*)d_in[4];
  const int* mask_len = (const int*)d_in[5];
  float* out = (float*)d_out;

  u16* ws = (u16*)d_ws;
  u16* xb    = ws;                              // 4M elems (x bf16) — reused as Y later
  u16* wqkvt = ws + (size_t)4 * 1024 * 1024;    // 3M (W_qkv^T bf16)
  u16* wot   = wqkvt + (size_t)3 * 1024 * 1024; // 1M (W_o^T bf16)
  u16* Qb    = wot + (size_t)1024 * 1024;       // 4M
  u16* Kb    = Qb + (size_t)4 * 1024 * 1024;    // 4M
  u16* Vtb   = Kb + (size_t)4 * 1024 * 1024;    // 4M
  u16* Yb    = xb;                              // alias: x dead after gemm_qkv

  prep<<<6144, 256, 0, stream>>>(x, xb, Wqkv, wqkvt, Wo, wot);
  gemm_bt<3072, 0, 128><<<dim3(24, 32), 256, 0, stream>>>(xb, wqkvt, bqkv, nullptr, Qb, Kb, Vtb);
  attn_fwd<<<1056, 256, 0, stream>>>(Qb, Kb, Vtb, mask_len, Yb);
  gemm_bt<1024, 1, 64><<<dim3(8, 64), 256, 0, stream>>>(Yb, wot, bo, out, nullptr, nullptr, nullptr);
}